// Round 12
// baseline (59.833 us; speedup 1.0000x reference)
//
#include <hip/hip_runtime.h>

#define NBINS 100
#define NROWS 101          // row 100 = spill slot for x -> 1.0 boundary (discarded)
#define BLK   64           // one wave per block; column == lane (exclusive)
#define GRID  1536         // 6 blocks/CU (LDS ~25.9 KB/block)
#define REP   8            // global accumulator replicas (atomic contention relief)

typedef unsigned int       u32;
typedef unsigned long long u64;

// Per-element: u = round(x*102400) -> k = u>>10 (bin), ti = u&1023 (frac 1/1024).
// Column cell (u32): (N << 20) + sum(ti).  Per-lane <=683 elems -> T < 2^20.
// Global cell (u64): (N << 37) + T_total.  Exact integer accumulation.
// count[b] = 0.01 * (N_b + (T_{b-1} - T_b)/1024);  out = count / (sum + 1e-6).

__global__ void histo_zero(u64* __restrict__ g) {
    int i = blockIdx.x * blockDim.x + threadIdx.x;
    if (i < REP * NBINS) g[i] = 0ull;
}

__global__ __launch_bounds__(BLK) void histo_accum(const float* __restrict__ x,
                                                   u64* __restrict__ g,
                                                   int n4, int n) {
    __shared__ u32 h[NROWS * BLK];
    const int lane = threadIdx.x;

    for (int i = lane; i < NROWS * BLK; i += BLK) h[i] = 0u;
    __syncthreads();

// R6's proven G=2 batch: both reads issue before either write; same-bin
// collision merged in registers ("last write wins" on the merged weight).
#define PROC2(va, vb) {                                        \
        u32 u0 = (u32)((va) * 102400.0f + 0.5f);               \
        u32 u1 = (u32)((vb) * 102400.0f + 0.5f);               \
        u32 k0 = u0 >> 10, k1 = u1 >> 10;                      \
        u32 w0 = (1u << 20) + (u0 & 1023u);                    \
        u32 w1 = (1u << 20) + (u1 & 1023u);                    \
        bool eq = (k0 == k1);                                  \
        u32 w1m = w1 + (eq ? w0 : 0u);                         \
        u32 w0m = eq ? 0u : w0;                                \
        int a0 = (int)(k0 * BLK) + lane;                       \
        int a1 = (int)(k1 * BLK) + lane;                       \
        u32 d0 = h[a0];                                        \
        u32 d1 = h[a1];                                        \
        h[a0] = d0 + w0m;                                      \
        h[a1] = d1 + w1m;                                      \
    }

#define PROC1(va) {                                            \
        u32 u0 = (u32)((va) * 102400.0f + 0.5f);               \
        u32 k0 = u0 >> 10;                                     \
        int a0 = (int)(k0 * BLK) + lane;                       \
        h[a0] += (1u << 20) + (u0 & 1023u);                    \
    }

#define PROC2x2(v) { PROC2((v).x, (v).y); PROC2((v).z, (v).w); }

    const float4* __restrict__ x4 = (const float4*)x;
    const int stride = gridDim.x * BLK;
    int i = blockIdx.x * BLK + lane;

    // THE one change vs R6: 16 float4 loads in flight per lane (256 B) instead
    // of 8 — doubles the VMEM queue depth per CU (48 -> 96 KB nominal) to push
    // past the Little's-law knee measured at ~5.36 TB/s. Plain indexed cached
    // loads, same grid-stride addressing as R6.
    for (; i + 15 * stride < n4; i += 16 * stride) {
        float4 v0  = x4[i];
        float4 v1  = x4[i + 1 * stride];
        float4 v2  = x4[i + 2 * stride];
        float4 v3  = x4[i + 3 * stride];
        float4 v4  = x4[i + 4 * stride];
        float4 v5  = x4[i + 5 * stride];
        float4 v6  = x4[i + 6 * stride];
        float4 v7  = x4[i + 7 * stride];
        float4 v8  = x4[i + 8 * stride];
        float4 v9  = x4[i + 9 * stride];
        float4 v10 = x4[i + 10 * stride];
        float4 v11 = x4[i + 11 * stride];
        float4 v12 = x4[i + 12 * stride];
        float4 v13 = x4[i + 13 * stride];
        float4 v14 = x4[i + 14 * stride];
        float4 v15 = x4[i + 15 * stride];
        PROC2x2(v0);  PROC2x2(v1);  PROC2x2(v2);  PROC2x2(v3);
        PROC2x2(v4);  PROC2x2(v5);  PROC2x2(v6);  PROC2x2(v7);
        PROC2x2(v8);  PROC2x2(v9);  PROC2x2(v10); PROC2x2(v11);
        PROC2x2(v12); PROC2x2(v13); PROC2x2(v14); PROC2x2(v15);
    }
    for (; i < n4; i += stride) {
        float4 v = x4[i];
        PROC2x2(v);
    }
    if (blockIdx.x == 0) {               // scalar tail (n % 4)
        for (int t = n4 * 4 + lane; t < n; t += BLK) { float v = x[t]; PROC1(v); }
    }
#undef PROC2x2
#undef PROC1
#undef PROC2

    __syncthreads();

    // Reduce 64 columns/bin (diagonal sweep: bank = (c+lane)%32, 2-way = free),
    // one packed-u64 global atomic per bin per block (8 replicas).
    u64* grep = &g[(blockIdx.x & (REP - 1)) * NBINS];
    for (int b = lane; b < NBINS; b += BLK) {
        u32 Ns = 0, Ts = 0;
#pragma unroll
        for (int c = 0; c < BLK; ++c) {
            int cc = (c + lane) & (BLK - 1);
            u32 u = h[b * BLK + cc];
            Ns += u >> 20;
            Ts += u & 0xFFFFFu;
        }
        atomicAdd(&grep[b], ((u64)Ns << 37) + (u64)Ts);
    }
}

__global__ void histo_final(const u64* __restrict__ g, float* __restrict__ out) {
    __shared__ float Tprev[NBINS + 1];
    __shared__ float wsum[2];
    const int t = threadIdx.x;           // 128 threads = 2 waves

    float N = 0.0f, T = 0.0f;
    if (t < NBINS) {
        u64 acc = 0ull;
#pragma unroll
        for (int r = 0; r < REP; ++r) acc += g[r * NBINS + t];
        N = (float)(acc >> 37);
        T = (float)(acc & ((1ull << 37) - 1ull));
        Tprev[t + 1] = T;
    }
    if (t == 127) Tprev[0] = 0.0f;
    __syncthreads();

    float c = 0.0f;
    if (t < NBINS) c = 0.01f * (N + (Tprev[t] - T) * (1.0f / 1024.0f));

    float s = c;
#pragma unroll
    for (int o = 32; o > 0; o >>= 1) s += __shfl_down(s, o, 64);
    if ((t & 63) == 0) wsum[t >> 6] = s;
    __syncthreads();

    float total = wsum[0] + wsum[1];
    if (t < NBINS) out[t] = c / (total + 1e-6f);
}

extern "C" void kernel_launch(void* const* d_in, const int* in_sizes, int n_in,
                              void* d_out, int out_size, void* d_ws, size_t ws_size,
                              hipStream_t stream) {
    const float* x   = (const float*)d_in[0];  // [64 * 1048576] fp32 in [0,1)
    float*       out = (float*)d_out;          // [100] fp32
    u64*         g   = (u64*)d_ws;             // REP*100 u64 accumulators

    const int n  = in_sizes[0];
    const int n4 = n / 4;

    histo_zero<<<(REP * NBINS + 255) / 256, 256, 0, stream>>>(g);

    int blocks = GRID;
    int need   = (n4 + BLK - 1) / BLK;
    if (blocks > need) blocks = need;
    histo_accum<<<blocks, BLK, 0, stream>>>(x, g, n4, n);

    histo_final<<<1, 128, 0, stream>>>(g, out);
}

// Round 14
// 57.714 us; speedup vs baseline: 1.0367x; 1.0367x over previous
//
#include <hip/hip_runtime.h>

#define NBINS 100
#define NROWS 101          // row 100 = spill slot for x -> 1.0 boundary (discarded)
#define BLK   64           // one wave per block; column == lane (exclusive)
#define GRID  1536         // 6 blocks/CU (LDS ~25.9 KB/block)
#define REP   8            // global accumulator replicas (atomic contention relief)

typedef unsigned int       u32;
typedef unsigned long long u64;
typedef float f32x4 __attribute__((ext_vector_type(4)));   // native clang vector
                                                            // (nt builtin rejects
                                                            // HIP_vector_type)

// Per-element: u = round(x*102400) -> k = u>>10 (bin), ti = u&1023 (frac 1/1024).
// Column cell (u32): (N << 20) + sum(ti).  Per-lane <=683 elems -> T < 2^20.
// Global cell (u64): (N << 37) + T_total.  Exact integer accumulation.
// count[b] = 0.01 * (N_b + (T_{b-1} - T_b)/1024);  out = count / (sum + 1e-6).

__global__ void histo_zero(u64* __restrict__ g) {
    int i = blockIdx.x * blockDim.x + threadIdx.x;
    if (i < REP * NBINS) g[i] = 0ull;
}

__global__ __launch_bounds__(BLK) void histo_accum(const float* __restrict__ x,
                                                   u64* __restrict__ g,
                                                   int n4, int n) {
    __shared__ u32 h[NROWS * BLK];
    const int lane = threadIdx.x;

    for (int i = lane; i < NROWS * BLK; i += BLK) h[i] = 0u;
    __syncthreads();

// R6's proven G=2 batch: both reads issue before either write; same-bin
// collision merged in registers ("last write wins" on the merged weight).
#define PROC2(va, vb) {                                        \
        u32 u0 = (u32)((va) * 102400.0f + 0.5f);               \
        u32 u1 = (u32)((vb) * 102400.0f + 0.5f);               \
        u32 k0 = u0 >> 10, k1 = u1 >> 10;                      \
        u32 w0 = (1u << 20) + (u0 & 1023u);                    \
        u32 w1 = (1u << 20) + (u1 & 1023u);                    \
        bool eq = (k0 == k1);                                  \
        u32 w1m = w1 + (eq ? w0 : 0u);                         \
        u32 w0m = eq ? 0u : w0;                                \
        int a0 = (int)(k0 * BLK) + lane;                       \
        int a1 = (int)(k1 * BLK) + lane;                       \
        u32 d0 = h[a0];                                        \
        u32 d1 = h[a1];                                        \
        h[a0] = d0 + w0m;                                      \
        h[a1] = d1 + w1m;                                      \
    }

#define PROC1(va) {                                            \
        u32 u0 = (u32)((va) * 102400.0f + 0.5f);               \
        u32 k0 = u0 >> 10;                                     \
        int a0 = (int)(k0 * BLK) + lane;                       \
        h[a0] += (1u << 20) + (u0 & 1023u);                    \
    }

#define PROC2x2(v) { PROC2((v).x, (v).y); PROC2((v).z, (v).w); }

    const f32x4* __restrict__ x4 = (const f32x4*)x;
    const int stride = gridDim.x * BLK;
    int i = blockIdx.x * BLK + lane;

    // THE one change vs R6: nontemporal (nt) loads — read-once 268 MB stream
    // bypasses L2 allocation priority. Everything else structurally R6.
    for (; i + 7 * stride < n4; i += 8 * stride) {
        f32x4 v0 = __builtin_nontemporal_load(&x4[i]);
        f32x4 v1 = __builtin_nontemporal_load(&x4[i + 1 * stride]);
        f32x4 v2 = __builtin_nontemporal_load(&x4[i + 2 * stride]);
        f32x4 v3 = __builtin_nontemporal_load(&x4[i + 3 * stride]);
        f32x4 v4 = __builtin_nontemporal_load(&x4[i + 4 * stride]);
        f32x4 v5 = __builtin_nontemporal_load(&x4[i + 5 * stride]);
        f32x4 v6 = __builtin_nontemporal_load(&x4[i + 6 * stride]);
        f32x4 v7 = __builtin_nontemporal_load(&x4[i + 7 * stride]);
        PROC2x2(v0); PROC2x2(v1); PROC2x2(v2); PROC2x2(v3);
        PROC2x2(v4); PROC2x2(v5); PROC2x2(v6); PROC2x2(v7);
    }
    for (; i < n4; i += stride) {
        f32x4 v = __builtin_nontemporal_load(&x4[i]);
        PROC2x2(v);
    }
    if (blockIdx.x == 0) {               // scalar tail (n % 4)
        for (int t = n4 * 4 + lane; t < n; t += BLK) { float v = x[t]; PROC1(v); }
    }
#undef PROC2x2
#undef PROC1
#undef PROC2

    __syncthreads();

    // Reduce 64 columns/bin (diagonal sweep: bank = (c+lane)%32, 2-way = free),
    // one packed-u64 global atomic per bin per block (8 replicas).
    u64* grep = &g[(blockIdx.x & (REP - 1)) * NBINS];
    for (int b = lane; b < NBINS; b += BLK) {
        u32 Ns = 0, Ts = 0;
#pragma unroll
        for (int c = 0; c < BLK; ++c) {
            int cc = (c + lane) & (BLK - 1);
            u32 u = h[b * BLK + cc];
            Ns += u >> 20;
            Ts += u & 0xFFFFFu;
        }
        atomicAdd(&grep[b], ((u64)Ns << 37) + (u64)Ts);
    }
}

__global__ void histo_final(const u64* __restrict__ g, float* __restrict__ out) {
    __shared__ float Tprev[NBINS + 1];
    __shared__ float wsum[2];
    const int t = threadIdx.x;           // 128 threads = 2 waves

    float N = 0.0f, T = 0.0f;
    if (t < NBINS) {
        u64 acc = 0ull;
#pragma unroll
        for (int r = 0; r < REP; ++r) acc += g[r * NBINS + t];
        N = (float)(acc >> 37);
        T = (float)(acc & ((1ull << 37) - 1ull));
        Tprev[t + 1] = T;
    }
    if (t == 127) Tprev[0] = 0.0f;
    __syncthreads();

    float c = 0.0f;
    if (t < NBINS) c = 0.01f * (N + (Tprev[t] - T) * (1.0f / 1024.0f));

    float s = c;
#pragma unroll
    for (int o = 32; o > 0; o >>= 1) s += __shfl_down(s, o, 64);
    if ((t & 63) == 0) wsum[t >> 6] = s;
    __syncthreads();

    float total = wsum[0] + wsum[1];
    if (t < NBINS) out[t] = c / (total + 1e-6f);
}

extern "C" void kernel_launch(void* const* d_in, const int* in_sizes, int n_in,
                              void* d_out, int out_size, void* d_ws, size_t ws_size,
                              hipStream_t stream) {
    const float* x   = (const float*)d_in[0];  // [64 * 1048576] fp32 in [0,1)
    float*       out = (float*)d_out;          // [100] fp32
    u64*         g   = (u64*)d_ws;             // REP*100 u64 accumulators

    const int n  = in_sizes[0];
    const int n4 = n / 4;

    histo_zero<<<(REP * NBINS + 255) / 256, 256, 0, stream>>>(g);

    int blocks = GRID;
    int need   = (n4 + BLK - 1) / BLK;
    if (blocks > need) blocks = need;
    histo_accum<<<blocks, BLK, 0, stream>>>(x, g, n4, n);

    histo_final<<<1, 128, 0, stream>>>(g, out);
}